// Round 2
// 1561.027 us; speedup vs baseline: 1.1598x; 1.1598x over previous
//
#include <hip/hip_runtime.h>
#include <hip/hip_bf16.h>

typedef __bf16 bf16_t;
typedef __bf16 bf16x8 __attribute__((ext_vector_type(8)));
typedef float floatx4 __attribute__((ext_vector_type(4)));

#define D_MODEL 768
#define N_HEADS 12
#define DK 64
#define SEQ 1024
#define BATCH 2
#define NROWS (BATCH * SEQ)
#define FFN 3072
#define VOCAB 32000
#define N_LAYERS 4
#define LN_EPS 1e-5f

// ---------------------------------------------------------------- reductions
__device__ __forceinline__ float block_reduce_256(float v, bool is_max, float* sb) {
#pragma unroll
    for (int off = 32; off > 0; off >>= 1) {
        float o = __shfl_down(v, off, 64);
        v = is_max ? fmaxf(v, o) : (v + o);
    }
    int lane = threadIdx.x & 63, wid = threadIdx.x >> 6;
    if (lane == 0) sb[wid] = v;
    __syncthreads();
    float r = is_max ? fmaxf(fmaxf(sb[0], sb[1]), fmaxf(sb[2], sb[3]))
                     : (sb[0] + sb[1]) + (sb[2] + sb[3]);
    __syncthreads();
    return r;
}

// ---------------------------------------------------------------- embedding
__global__ __launch_bounds__(256) void embed_kernel(const int* __restrict__ x,
                                                    const float* __restrict__ tok,
                                                    const float* __restrict__ pos,
                                                    float* __restrict__ h) {
    int row = blockIdx.x;
    int s = row & (SEQ - 1);
    int t = x[row];
    const float* te = tok + (size_t)t * D_MODEL;
    const float* pe = pos + (size_t)s * D_MODEL;
    float* out = h + (size_t)row * D_MODEL;
    int tid = threadIdx.x;
    out[tid]       = te[tid]       + pe[tid];
    out[tid + 256] = te[tid + 256] + pe[tid + 256];
    out[tid + 512] = te[tid + 512] + pe[tid + 512];
}

// ---------------------------------------------------------------- fp32 -> bf16 convert (8 elems/thread)
__global__ __launch_bounds__(256) void cvt_bf16_kernel(const float* __restrict__ src,
                                                       bf16_t* __restrict__ dst) {
    size_t i = ((size_t)blockIdx.x * 256 + threadIdx.x) * 8;
    const float4 a = *(const float4*)(src + i);
    const float4 b = *(const float4*)(src + i + 4);
    bf16x8 o;
    o[0] = (bf16_t)a.x; o[1] = (bf16_t)a.y; o[2] = (bf16_t)a.z; o[3] = (bf16_t)a.w;
    o[4] = (bf16_t)b.x; o[5] = (bf16_t)b.y; o[6] = (bf16_t)b.z; o[7] = (bf16_t)b.w;
    *(bf16x8*)(dst + i) = o;
}
static_assert((VOCAB * D_MODEL) % (256 * 8) == 0, "cvt grid must tile exactly");

// ---------------------------------------------------------------- layernorm
__global__ __launch_bounds__(256) void ln_kernel(const float* __restrict__ h,
                                                 const float* __restrict__ g,
                                                 const float* __restrict__ b,
                                                 bf16_t* __restrict__ y) {
    __shared__ float sb[4];
    int row = blockIdx.x;
    const float* xr = h + (size_t)row * D_MODEL;
    int t = threadIdx.x;
    float v0 = xr[t], v1 = xr[t + 256], v2 = xr[t + 512];
    float s  = block_reduce_256(v0 + v1 + v2, false, sb);
    float s2 = block_reduce_256(v0 * v0 + v1 * v1 + v2 * v2, false, sb);
    float mu  = s * (1.0f / D_MODEL);
    float var = s2 * (1.0f / D_MODEL) - mu * mu;
    float inv = rsqrtf(var + LN_EPS);
    bf16_t* yr = y + (size_t)row * D_MODEL;
    yr[t]       = (bf16_t)((v0 - mu) * inv * g[t]       + b[t]);
    yr[t + 256] = (bf16_t)((v1 - mu) * inv * g[t + 256] + b[t + 256]);
    yr[t + 512] = (bf16_t)((v2 - mu) * inv * g[t + 512] + b[t + 512]);
}

// ---------------------------------------------------------------- GEMM: C = A(MxK,bf16) . W(NxK,fp32)^T  (+bias)(+relu)(+res)
template <typename OutT, bool RELU, bool HAS_BIAS, bool HAS_RES, bool MSWAP>
__global__ __launch_bounds__(256) void gemm_bt(const bf16_t* __restrict__ A,
                                               const float* __restrict__ W,
                                               const float* __restrict__ bias,
                                               const float* __restrict__ res,
                                               OutT* __restrict__ C,
                                               int M, int N, int K) {
    const int LDR = 40;
    __shared__ bf16_t As[64 * LDR];
    __shared__ bf16_t Bs[64 * LDR];
    const int m0 = (MSWAP ? blockIdx.x : blockIdx.y) * 64;
    const int n0 = (MSWAP ? blockIdx.y : blockIdx.x) * 64;
    const int tid  = threadIdx.x;
    const int wave = tid >> 6;
    const int lane = tid & 63;
    const int q    = lane >> 4;
    const int ln16 = lane & 15;

    floatx4 acc[4] = {{0.f, 0.f, 0.f, 0.f}, {0.f, 0.f, 0.f, 0.f},
                      {0.f, 0.f, 0.f, 0.f}, {0.f, 0.f, 0.f, 0.f}};

    const int srow = tid >> 2;
    const int scol = (tid & 3) * 8;
    const bf16_t* Aptr = A + (size_t)(m0 + srow) * K + scol;
    const float*  Wptr = W + (size_t)(n0 + srow) * K + scol;

    for (int k0 = 0; k0 < K; k0 += 32) {
        *(uint4*)(&As[srow * LDR + scol]) = *(const uint4*)(Aptr + k0);
        float4 w0 = *(const float4*)(Wptr + k0);
        float4 w1 = *(const float4*)(Wptr + k0 + 4);
        bf16x8 wb;
        wb[0] = (bf16_t)w0.x; wb[1] = (bf16_t)w0.y; wb[2] = (bf16_t)w0.z; wb[3] = (bf16_t)w0.w;
        wb[4] = (bf16_t)w1.x; wb[5] = (bf16_t)w1.y; wb[6] = (bf16_t)w1.z; wb[7] = (bf16_t)w1.w;
        *(bf16x8*)(&Bs[srow * LDR + scol]) = wb;
        __syncthreads();
        const bf16x8 a = *(const bf16x8*)(&As[(wave * 16 + ln16) * LDR + q * 8]);
#pragma unroll
        for (int nt = 0; nt < 4; nt++) {
            const bf16x8 b = *(const bf16x8*)(&Bs[(nt * 16 + ln16) * LDR + q * 8]);
            acc[nt] = __builtin_amdgcn_mfma_f32_16x16x32_bf16(a, b, acc[nt], 0, 0, 0);
        }
        __syncthreads();
    }

#pragma unroll
    for (int nt = 0; nt < 4; nt++) {
        const int n = n0 + nt * 16 + ln16;
        float bv = 0.f;
        if constexpr (HAS_BIAS) bv = bias[n];
#pragma unroll
        for (int r = 0; r < 4; r++) {
            const int m = m0 + wave * 16 + q * 4 + r;
            float v = acc[nt][r] + bv;
            if constexpr (RELU) v = fmaxf(v, 0.f);
            if constexpr (HAS_RES) v += res[(size_t)m * N + n];
            C[(size_t)m * N + n] = (OutT)v;
        }
    }
}

// ---------------------------------------------------------------- 128x128 bf16xbf16 GEMM (m97 structure)
// C(fp32) = A(MxK bf16) . W(NxK bf16)^T. 4 waves (2x2), each wave owns a 64x64 sub-tile
// (4x4 fragments of 16x16). Staging via global_load_lds width=16 into linear [128][32] LDS.
// grid = (M/128, N/128): m-fastest dispatch so consecutive blocks share the W panel (L2 reuse).
typedef __attribute__((address_space(3))) unsigned int lds_uint;
typedef const __attribute__((address_space(1))) unsigned int glb_uint;
__device__ __forceinline__ void gload16(const bf16_t* g, bf16_t* l) {
    __builtin_amdgcn_global_load_lds((glb_uint*)g, (lds_uint*)l, 16, 0, 0);
}

__global__ __launch_bounds__(256) void gemm_bt128(const bf16_t* __restrict__ A,
                                                  const bf16_t* __restrict__ W,
                                                  float* __restrict__ C,
                                                  int M, int N, int K) {
    __shared__ __align__(16) bf16_t As[128 * 32];
    __shared__ __align__(16) bf16_t Bs[128 * 32];
    const int m0 = blockIdx.x * 128;
    const int n0 = blockIdx.y * 128;
    const int tid  = threadIdx.x;
    const int wave = tid >> 6;
    const int lane = tid & 63;
    const int q    = lane >> 4;
    const int ln16 = lane & 15;
    const int wr   = wave >> 1;           // 0..1: row half of C tile
    const int wc   = wave & 1;            // 0..1: col half of C tile

    floatx4 acc[4][4];
#pragma unroll
    for (int i = 0; i < 4; i++)
#pragma unroll
        for (int j = 0; j < 4; j++) acc[i][j] = (floatx4){0.f, 0.f, 0.f, 0.f};

    // staging: wave covers rows wave*32..wave*32+31 of the 128-row tile.
    // global_load_lds dest = wave-uniform base + lane*16B -> lane l = (row l/4, col (l&3)*8).
    const int srow = lane >> 2;           // 0..15
    const int scol = (lane & 3) * 8;
    const bf16_t* Ag = A + (size_t)(m0 + wave * 32 + srow) * K + scol;
    const bf16_t* Wg = W + (size_t)(n0 + wave * 32 + srow) * K + scol;
    bf16_t* As0 = &As[wave * 1024];       // 32 rows * 32 cols per wave
    bf16_t* Bs0 = &Bs[wave * 1024];

    for (int k0 = 0; k0 < K; k0 += 32) {
        gload16(Ag + k0, As0);
        gload16(Ag + (size_t)16 * K + k0, As0 + 512);
        gload16(Wg + k0, Bs0);
        gload16(Wg + (size_t)16 * K + k0, Bs0 + 512);
        __syncthreads();                  // compiler drains vmcnt(0) before s_barrier: tile visible
        bf16x8 af[4], bfg[4];
#pragma unroll
        for (int mt = 0; mt < 4; mt++)
            af[mt] = *(const bf16x8*)&As[(wr * 64 + mt * 16 + ln16) * 32 + q * 8];
#pragma unroll
        for (int nt = 0; nt < 4; nt++)
            bfg[nt] = *(const bf16x8*)&Bs[(wc * 64 + nt * 16 + ln16) * 32 + q * 8];
#pragma unroll
        for (int mt = 0; mt < 4; mt++)
#pragma unroll
            for (int nt = 0; nt < 4; nt++)
                acc[mt][nt] = __builtin_amdgcn_mfma_f32_16x16x32_bf16(af[mt], bfg[nt], acc[mt][nt], 0, 0, 0);
        __syncthreads();                  // all reads done before next stage overwrites
    }

#pragma unroll
    for (int mt = 0; mt < 4; mt++)
#pragma unroll
        for (int nt = 0; nt < 4; nt++) {
            const int n = n0 + wc * 64 + nt * 16 + ln16;
#pragma unroll
            for (int r = 0; r < 4; r++) {
                const int m = m0 + wr * 64 + mt * 16 + q * 4 + r;
                C[(size_t)m * N + n] = acc[mt][nt][r];
            }
        }
}

// ---------------------------------------------------------------- flash attention
// One block per (q-tile of 64 rows, b*h). 4 waves; wave w owns q rows w*16..w*16+15.
// Q,K,V bf16 [2048, 768]; head slice cols hh*64..+63. Online softmax, MFMA QK^T & PV.
__global__ __launch_bounds__(256) void attn_kernel(const bf16_t* __restrict__ Q,
                                                   const bf16_t* __restrict__ K,
                                                   const bf16_t* __restrict__ V,
                                                   bf16_t* __restrict__ ctx) {
    // LDS: Qs [0,4096) elems (reused as Ps after Q-frag hoist), Ks [4096,8192), Vts [8192,12288)
    __shared__ bf16_t smem[12288];
    bf16_t* Qs  = smem;
    bf16_t* Ks  = smem + 4096;
    bf16_t* Vts = smem + 8192;
    bf16_t* Ps  = smem;                      // aliases Qs (dead after frag hoist)

    const int qt  = blockIdx.x;              // 0..15
    const int bh  = blockIdx.y;              // 0..23
    const int b   = bh / N_HEADS;
    const int hh  = bh - b * N_HEADS;
    const int tid  = threadIdx.x;
    const int wave = tid >> 6;
    const int lane = tid & 63;
    const int quad = lane >> 4;
    const int ln16 = lane & 15;
    const int q0   = qt * 64;
    const size_t base = (size_t)(b * SEQ) * D_MODEL + hh * DK;

    const int r0 = tid >> 3;                 // 0..31 staging row
    const int cg = tid & 7;                  // col group (8 elems)

    // ---- stage Q tile (natural layout), hoist A-frags
    {
        const bf16_t* src = Q + base + (size_t)q0 * D_MODEL;
        *(uint4*)&Qs[r0 * 64 + cg * 8]        = *(const uint4*)(src + (size_t)r0 * D_MODEL + cg * 8);
        *(uint4*)&Qs[(r0 + 32) * 64 + cg * 8] = *(const uint4*)(src + (size_t)(r0 + 32) * D_MODEL + cg * 8);
    }
    __syncthreads();
    const bf16x8 aq0 = *(const bf16x8*)&Qs[(wave * 16 + ln16) * 64 + quad * 8];
    const bf16x8 aq1 = *(const bf16x8*)&Qs[(wave * 16 + ln16) * 64 + 32 + quad * 8];

    float m_run[4] = {-1e30f, -1e30f, -1e30f, -1e30f};
    float l_run[4] = {0.f, 0.f, 0.f, 0.f};
    floatx4 o[4] = {{0.f, 0.f, 0.f, 0.f}, {0.f, 0.f, 0.f, 0.f},
                    {0.f, 0.f, 0.f, 0.f}, {0.f, 0.f, 0.f, 0.f}};
    const float scale = 0.125f;              // 1/sqrt(64)

    for (int j0 = 0; j0 <= q0; j0 += 64) {
        __syncthreads();                     // prev iter's reads done before restage (iter0: Q-frags hoisted)
        // ---- stage K (natural) and V (transposed + xor-swizzled)
        const bf16_t* ksrc = K + base + (size_t)j0 * D_MODEL;
        const bf16_t* vsrc = V + base + (size_t)j0 * D_MODEL;
#pragma unroll
        for (int half = 0; half < 2; half++) {
            const int j = r0 + half * 32;
            *(uint4*)&Ks[j * 64 + cg * 8] = *(const uint4*)(ksrc + (size_t)j * D_MODEL + cg * 8);
            const bf16x8 vv = *(const bf16x8*)(vsrc + (size_t)j * D_MODEL + cg * 8);
#pragma unroll
            for (int i = 0; i < 8; i++) {
                const int d = cg * 8 + i;
                Vts[d * 64 + (((j >> 3) ^ cg) << 3) + (j & 7)] = vv[i];
            }
        }
        __syncthreads();

        // ---- S = (Q K^T) * scale   (C-layout: row=quad*4+r, col=nt*16+ln16)
        floatx4 s[4];
#pragma unroll
        for (int nt = 0; nt < 4; nt++) {
            const bf16x8 bk0 = *(const bf16x8*)&Ks[(nt * 16 + ln16) * 64 + quad * 8];
            const bf16x8 bk1 = *(const bf16x8*)&Ks[(nt * 16 + ln16) * 64 + 32 + quad * 8];
            floatx4 z = {0.f, 0.f, 0.f, 0.f};
            z = __builtin_amdgcn_mfma_f32_16x16x32_bf16(aq0, bk0, z, 0, 0, 0);
            z = __builtin_amdgcn_mfma_f32_16x16x32_bf16(aq1, bk1, z, 0, 0, 0);
            s[nt] = z;
        }
        const bool diag = (j0 == q0);
#pragma unroll
        for (int nt = 0; nt < 4; nt++)
#pragma unroll
            for (int r = 0; r < 4; r++) {
                float v = s[nt][r] * scale;
                if (diag && (nt * 16 + ln16 > wave * 16 + quad * 4 + r)) v = -1e30f;
                s[nt][r] = v;
            }

        // ---- online softmax update (rows quad*4+r; reduce over 16 lanes)
        float alpha[4];
#pragma unroll
        for (int r = 0; r < 4; r++) {
            float v = fmaxf(fmaxf(s[0][r], s[1][r]), fmaxf(s[2][r], s[3][r]));
#pragma unroll
            for (int off = 1; off < 16; off <<= 1) v = fmaxf(v, __shfl_xor(v, off, 64));
            const float m_new = fmaxf(m_run[r], v);
            alpha[r] = __expf(m_run[r] - m_new);
            m_run[r] = m_new;
        }
        float rsum[4] = {0.f, 0.f, 0.f, 0.f};
#pragma unroll
        for (int nt = 0; nt < 4; nt++)
#pragma unroll
            for (int r = 0; r < 4; r++) {
                const float p = __expf(s[nt][r] - m_run[r]);
                s[nt][r] = p;
                rsum[r] += p;
            }
#pragma unroll
        for (int r = 0; r < 4; r++) {
            float v = rsum[r];
#pragma unroll
            for (int off = 1; off < 16; off <<= 1) v += __shfl_xor(v, off, 64);
            l_run[r] = l_run[r] * alpha[r] + v;
        }
#pragma unroll
        for (int nt = 0; nt < 4; nt++)
#pragma unroll
            for (int r = 0; r < 4; r++) o[nt][r] *= alpha[r];

        // ---- P: C-layout regs -> per-wave LDS (xor-swizzled) -> A-layout frags
        bf16_t* Pw = Ps + wave * 1024;
#pragma unroll
        for (int nt = 0; nt < 4; nt++)
#pragma unroll
            for (int r = 0; r < 4; r++) {
                const int rr = quad * 4 + r;
                Pw[rr * 64 + (((nt * 2 + (ln16 >> 3)) ^ (rr & 7)) << 3) + (ln16 & 7)] = (bf16_t)s[nt][r];
            }
        const bf16x8 ap0 = *(const bf16x8*)&Pw[ln16 * 64 + ((quad ^ (ln16 & 7)) << 3)];
        const bf16x8 ap1 = *(const bf16x8*)&Pw[ln16 * 64 + (((quad + 4) ^ (ln16 & 7)) << 3)];

        // ---- O += P V   (B-frag from swizzled Vt: row d, k=j)
#pragma unroll
        for (int nt = 0; nt < 4; nt++) {
            const int d  = nt * 16 + ln16;
            const int dd = (nt * 2 + (ln16 >> 3)) & 7;
            const bf16x8 bv0 = *(const bf16x8*)&Vts[d * 64 + ((quad ^ dd) << 3)];
            const bf16x8 bv1 = *(const bf16x8*)&Vts[d * 64 + (((quad + 4) ^ dd) << 3)];
            o[nt] = __builtin_amdgcn_mfma_f32_16x16x32_bf16(ap0, bv0, o[nt], 0, 0, 0);
            o[nt] = __builtin_amdgcn_mfma_f32_16x16x32_bf16(ap1, bv1, o[nt], 0, 0, 0);
        }
    }

    // ---- epilogue: O / l -> ctx
#pragma unroll
    for (int r = 0; r < 4; r++) {
        const float inv = 1.0f / l_run[r];
        const int m = q0 + wave * 16 + quad * 4 + r;
#pragma unroll
        for (int nt = 0; nt < 4; nt++) {
            ctx[base + (size_t)m * D_MODEL + nt * 16 + ln16] = (bf16_t)(o[nt][r] * inv);
        }
    }
}

// ---------------------------------------------------------------- launch
extern "C" void kernel_launch(void* const* d_in, const int* in_sizes, int n_in,
                              void* d_out, int out_size, void* d_ws, size_t ws_size,
                              hipStream_t stream) {
    const int*   x    = (const int*)d_in[0];
    const float* tok  = (const float*)d_in[1];
    const float* pos  = (const float*)d_in[2];
    const float* Wq   = (const float*)d_in[3];
    const float* bq   = (const float*)d_in[4];
    const float* Wk   = (const float*)d_in[5];
    const float* bk   = (const float*)d_in[6];
    const float* Wv   = (const float*)d_in[7];
    const float* bv   = (const float*)d_in[8];
    const float* Wo   = (const float*)d_in[9];
    const float* bo   = (const float*)d_in[10];
    const float* W1   = (const float*)d_in[11];
    const float* b1   = (const float*)d_in[12];
    const float* W2   = (const float*)d_in[13];
    const float* b2   = (const float*)d_in[14];
    const float* ln1g = (const float*)d_in[15];
    const float* ln1b = (const float*)d_in[16];
    const float* ln2g = (const float*)d_in[17];
    const float* ln2b = (const float*)d_in[18];
    const float* lnfg = (const float*)d_in[19];
    const float* lnfb = (const float*)d_in[20];

    char* ws = (char*)d_ws;
    const size_t OFF_H   = 0;                   // fp32 [2048,768]
    const size_t OFF_Y   = 6291456;             // bf16 [2048,768]
    const size_t OFF_Q   = 9437184;             // bf16 [2048,768]
    const size_t OFF_K   = 12582912;            // bf16 [2048,768]
    const size_t OFF_V   = 15728640;            // bf16 [2048,768]
    const size_t OFF_CTX = 18874368;            // bf16 [2048,768]
    const size_t OFF_FF  = OFF_Q;               // bf16 [2048,3072] aliases Q+K+V+CTX (all dead)
    const size_t OFF_TOKB = 22020096;           // bf16 [32000,768] = 49,152,000 B (optional)
    const size_t TOKB_BYTES = (size_t)VOCAB * D_MODEL * 2;
    const bool big_ws = ws_size >= OFF_TOKB + TOKB_BYTES;

    float*  h    = (float*)(ws + OFF_H);
    bf16_t* y    = (bf16_t*)(ws + OFF_Y);
    bf16_t* qb   = (bf16_t*)(ws + OFF_Q);
    bf16_t* kb   = (bf16_t*)(ws + OFF_K);
    bf16_t* vbuf = (bf16_t*)(ws + OFF_V);
    bf16_t* ctx  = (bf16_t*)(ws + OFF_CTX);
    bf16_t* ff   = (bf16_t*)(ws + OFF_FF);
    bf16_t* tokb = (bf16_t*)(ws + OFF_TOKB);
    float*  outp = (float*)d_out;

    embed_kernel<<<NROWS, 256, 0, stream>>>(x, tok, pos, h);

    // pre-convert LM-head weights (tied tok_emb) to bf16 once per launch.
    // Same RTN cast as the in-kernel conversion -> numerics identical.
    if (big_ws) {
        cvt_bf16_kernel<<<(VOCAB * D_MODEL) / (256 * 8), 256, 0, stream>>>(tok, tokb);
    }

    const dim3 g768(D_MODEL / 64, NROWS / 64);
    const dim3 gffn(FFN / 64, NROWS / 64);
    const dim3 gattn(SEQ / 64, BATCH * N_HEADS);

    for (int l = 0; l < N_LAYERS; l++) {
        const float* Wq_l = Wq + (size_t)l * D_MODEL * D_MODEL;
        const float* Wk_l = Wk + (size_t)l * D_MODEL * D_MODEL;
        const float* Wv_l = Wv + (size_t)l * D_MODEL * D_MODEL;
        const float* Wo_l = Wo + (size_t)l * D_MODEL * D_MODEL;
        const float* W1_l = W1 + (size_t)l * FFN * D_MODEL;
        const float* W2_l = W2 + (size_t)l * D_MODEL * FFN;

        ln_kernel<<<NROWS, 256, 0, stream>>>(h, ln1g + l * D_MODEL, ln1b + l * D_MODEL, y);

        gemm_bt<bf16_t, false, true, false, false><<<g768, 256, 0, stream>>>(
            y, Wq_l, bq + l * D_MODEL, nullptr, qb, NROWS, D_MODEL, D_MODEL);
        gemm_bt<bf16_t, false, true, false, false><<<g768, 256, 0, stream>>>(
            y, Wk_l, bk + l * D_MODEL, nullptr, kb, NROWS, D_MODEL, D_MODEL);
        gemm_bt<bf16_t, false, true, false, false><<<g768, 256, 0, stream>>>(
            y, Wv_l, bv + l * D_MODEL, nullptr, vbuf, NROWS, D_MODEL, D_MODEL);

        attn_kernel<<<gattn, 256, 0, stream>>>(qb, kb, vbuf, ctx);

        gemm_bt<float, false, true, true, false><<<g768, 256, 0, stream>>>(
            ctx, Wo_l, bo + l * D_MODEL, h, h, NROWS, D_MODEL, D_MODEL);

        ln_kernel<<<NROWS, 256, 0, stream>>>(h, ln2g + l * D_MODEL, ln2b + l * D_MODEL, y);

        gemm_bt<bf16_t, true, true, false, false><<<gffn, 256, 0, stream>>>(
            y, W1_l, b1 + l * FFN, nullptr, ff, NROWS, FFN, D_MODEL);

        gemm_bt<float, false, true, true, false><<<g768, 256, 0, stream>>>(
            ff, W2_l, b2 + l * D_MODEL, h, h, NROWS, D_MODEL, FFN);
    }

    ln_kernel<<<NROWS, 256, 0, stream>>>(h, lnfg, lnfb, y);

    if (big_ws) {
        // 128x128 m97-structure GEMM, grid m-fastest: 16 consecutive blocks share one
        // 196 KB bf16 W-panel -> W fetched from HBM ~once instead of ~16x.
        gemm_bt128<<<dim3(NROWS / 128, VOCAB / 128), 256, 0, stream>>>(
            y, tokb, outp, NROWS, VOCAB, D_MODEL);
    } else {
        // fallback (small workspace): old kernel, but grid-swapped for W-panel L2 reuse
        gemm_bt<float, false, false, false, true><<<dim3(NROWS / 64, VOCAB / 64), 256, 0, stream>>>(
            y, tok, nullptr, nullptr, outp, NROWS, VOCAB, D_MODEL);
    }
}

// Round 3
// 1255.155 us; speedup vs baseline: 1.4425x; 1.2437x over previous
//
#include <hip/hip_runtime.h>
#include <hip/hip_bf16.h>

typedef __bf16 bf16_t;
typedef __bf16 bf16x8 __attribute__((ext_vector_type(8)));
typedef float floatx4 __attribute__((ext_vector_type(4)));

#define D_MODEL 768
#define N_HEADS 12
#define DK 64
#define SEQ 1024
#define BATCH 2
#define NROWS (BATCH * SEQ)
#define FFN 3072
#define VOCAB 32000
#define N_LAYERS 4
#define LN_EPS 1e-5f

// ---------------------------------------------------------------- reductions
__device__ __forceinline__ float block_reduce_256(float v, bool is_max, float* sb) {
#pragma unroll
    for (int off = 32; off > 0; off >>= 1) {
        float o = __shfl_down(v, off, 64);
        v = is_max ? fmaxf(v, o) : (v + o);
    }
    int lane = threadIdx.x & 63, wid = threadIdx.x >> 6;
    if (lane == 0) sb[wid] = v;
    __syncthreads();
    float r = is_max ? fmaxf(fmaxf(sb[0], sb[1]), fmaxf(sb[2], sb[3]))
                     : (sb[0] + sb[1]) + (sb[2] + sb[3]);
    __syncthreads();
    return r;
}

// ---------------------------------------------------------------- embedding
__global__ __launch_bounds__(256) void embed_kernel(const int* __restrict__ x,
                                                    const float* __restrict__ tok,
                                                    const float* __restrict__ pos,
                                                    float* __restrict__ h) {
    int row = blockIdx.x;
    int s = row & (SEQ - 1);
    int t = x[row];
    const float* te = tok + (size_t)t * D_MODEL;
    const float* pe = pos + (size_t)s * D_MODEL;
    float* out = h + (size_t)row * D_MODEL;
    int tid = threadIdx.x;
    out[tid]       = te[tid]       + pe[tid];
    out[tid + 256] = te[tid + 256] + pe[tid + 256];
    out[tid + 512] = te[tid + 512] + pe[tid + 512];
}

// ---------------------------------------------------------------- fp32 -> bf16 convert (8 elems/thread)
__global__ __launch_bounds__(256) void cvt_bf16_kernel(const float* __restrict__ src,
                                                       bf16_t* __restrict__ dst) {
    size_t i = ((size_t)blockIdx.x * 256 + threadIdx.x) * 8;
    const float4 a = *(const float4*)(src + i);
    const float4 b = *(const float4*)(src + i + 4);
    bf16x8 o;
    o[0] = (bf16_t)a.x; o[1] = (bf16_t)a.y; o[2] = (bf16_t)a.z; o[3] = (bf16_t)a.w;
    o[4] = (bf16_t)b.x; o[5] = (bf16_t)b.y; o[6] = (bf16_t)b.z; o[7] = (bf16_t)b.w;
    *(bf16x8*)(dst + i) = o;
}
static_assert((VOCAB * D_MODEL) % 2048 == 0, "cvt tiling");
static_assert((N_LAYERS * D_MODEL * D_MODEL) % 2048 == 0, "cvt tiling");
static_assert((N_LAYERS * FFN * D_MODEL) % 2048 == 0, "cvt tiling");

// ---------------------------------------------------------------- pack Wq/Wk/Wv -> [L][2304][768] bf16
__global__ __launch_bounds__(256) void pack_qkvw_kernel(const float* __restrict__ Wq,
                                                        const float* __restrict__ Wk,
                                                        const float* __restrict__ Wv,
                                                        bf16_t* __restrict__ dst) {
    size_t e = ((size_t)blockIdx.x * 256 + threadIdx.x) * 8;
    const int PER_L = 3 * D_MODEL * D_MODEL;      // 1769472
    const int SEG   = D_MODEL * D_MODEL;          // 589824
    int l   = (int)(e / PER_L);
    int rem = (int)(e - (size_t)l * PER_L);
    int n   = rem / D_MODEL;                      // 0..2303
    int c   = rem - n * D_MODEL;
    int seg = n / D_MODEL;                        // 0,1,2
    int sr  = n - seg * D_MODEL;
    const float* src = (seg == 0 ? Wq : seg == 1 ? Wk : Wv) +
                       (size_t)l * SEG + (size_t)sr * D_MODEL + c;
    const float4 a = *(const float4*)src;
    const float4 b = *(const float4*)(src + 4);
    bf16x8 o;
    o[0] = (bf16_t)a.x; o[1] = (bf16_t)a.y; o[2] = (bf16_t)a.z; o[3] = (bf16_t)a.w;
    o[4] = (bf16_t)b.x; o[5] = (bf16_t)b.y; o[6] = (bf16_t)b.z; o[7] = (bf16_t)b.w;
    *(bf16x8*)(dst + e) = o;
}

// ---------------------------------------------------------------- pack bq/bk/bv -> [L][2304] fp32
__global__ __launch_bounds__(256) void pack_bias_kernel(const float* __restrict__ bq,
                                                        const float* __restrict__ bk,
                                                        const float* __restrict__ bv,
                                                        float* __restrict__ dst) {
    int i = blockIdx.x * 256 + threadIdx.x;       // < L*2304
    int l = i / (3 * D_MODEL);
    int n = i - l * (3 * D_MODEL);
    int seg = n / D_MODEL;
    int sr  = n - seg * D_MODEL;
    dst[i] = (seg == 0 ? bq : seg == 1 ? bk : bv)[l * D_MODEL + sr];
}

// ---------------------------------------------------------------- layernorm
__global__ __launch_bounds__(256) void ln_kernel(const float* __restrict__ h,
                                                 const float* __restrict__ g,
                                                 const float* __restrict__ b,
                                                 bf16_t* __restrict__ y) {
    __shared__ float sb[4];
    int row = blockIdx.x;
    const float* xr = h + (size_t)row * D_MODEL;
    int t = threadIdx.x;
    float v0 = xr[t], v1 = xr[t + 256], v2 = xr[t + 512];
    float s  = block_reduce_256(v0 + v1 + v2, false, sb);
    float s2 = block_reduce_256(v0 * v0 + v1 * v1 + v2 * v2, false, sb);
    float mu  = s * (1.0f / D_MODEL);
    float var = s2 * (1.0f / D_MODEL) - mu * mu;
    float inv = rsqrtf(var + LN_EPS);
    bf16_t* yr = y + (size_t)row * D_MODEL;
    yr[t]       = (bf16_t)((v0 - mu) * inv * g[t]       + b[t]);
    yr[t + 256] = (bf16_t)((v1 - mu) * inv * g[t + 256] + b[t + 256]);
    yr[t + 512] = (bf16_t)((v2 - mu) * inv * g[t + 512] + b[t + 512]);
}

// ---------------------------------------------------------------- legacy GEMM (fp32 W, 64x64) for fallback paths
template <typename OutT, bool RELU, bool HAS_BIAS, bool HAS_RES, bool MSWAP>
__global__ __launch_bounds__(256) void gemm_bt(const bf16_t* __restrict__ A,
                                               const float* __restrict__ W,
                                               const float* __restrict__ bias,
                                               const float* __restrict__ res,
                                               OutT* __restrict__ C,
                                               int M, int N, int K) {
    const int LDR = 40;
    __shared__ bf16_t As[64 * LDR];
    __shared__ bf16_t Bs[64 * LDR];
    const int m0 = (MSWAP ? blockIdx.x : blockIdx.y) * 64;
    const int n0 = (MSWAP ? blockIdx.y : blockIdx.x) * 64;
    const int tid  = threadIdx.x;
    const int wave = tid >> 6;
    const int lane = tid & 63;
    const int q    = lane >> 4;
    const int ln16 = lane & 15;

    floatx4 acc[4] = {{0.f, 0.f, 0.f, 0.f}, {0.f, 0.f, 0.f, 0.f},
                      {0.f, 0.f, 0.f, 0.f}, {0.f, 0.f, 0.f, 0.f}};

    const int srow = tid >> 2;
    const int scol = (tid & 3) * 8;
    const bf16_t* Aptr = A + (size_t)(m0 + srow) * K + scol;
    const float*  Wptr = W + (size_t)(n0 + srow) * K + scol;

    for (int k0 = 0; k0 < K; k0 += 32) {
        *(uint4*)(&As[srow * LDR + scol]) = *(const uint4*)(Aptr + k0);
        float4 w0 = *(const float4*)(Wptr + k0);
        float4 w1 = *(const float4*)(Wptr + k0 + 4);
        bf16x8 wb;
        wb[0] = (bf16_t)w0.x; wb[1] = (bf16_t)w0.y; wb[2] = (bf16_t)w0.z; wb[3] = (bf16_t)w0.w;
        wb[4] = (bf16_t)w1.x; wb[5] = (bf16_t)w1.y; wb[6] = (bf16_t)w1.z; wb[7] = (bf16_t)w1.w;
        *(bf16x8*)(&Bs[srow * LDR + scol]) = wb;
        __syncthreads();
        const bf16x8 a = *(const bf16x8*)(&As[(wave * 16 + ln16) * LDR + q * 8]);
#pragma unroll
        for (int nt = 0; nt < 4; nt++) {
            const bf16x8 b = *(const bf16x8*)(&Bs[(nt * 16 + ln16) * LDR + q * 8]);
            acc[nt] = __builtin_amdgcn_mfma_f32_16x16x32_bf16(a, b, acc[nt], 0, 0, 0);
        }
        __syncthreads();
    }

#pragma unroll
    for (int nt = 0; nt < 4; nt++) {
        const int n = n0 + nt * 16 + ln16;
        float bv = 0.f;
        if constexpr (HAS_BIAS) bv = bias[n];
#pragma unroll
        for (int r = 0; r < 4; r++) {
            const int m = m0 + wave * 16 + q * 4 + r;
            float v = acc[nt][r] + bv;
            if constexpr (RELU) v = fmaxf(v, 0.f);
            if constexpr (HAS_RES) v += res[(size_t)m * N + n];
            C[(size_t)m * N + n] = (OutT)v;
        }
    }
}

// ---------------------------------------------------------------- 128xTN bf16xbf16 GEMM (m97 structure, fused epilogue)
// C = A(MxK bf16) . W(NxK bf16)^T (+bias)(+relu)(+res). 4 waves (2x2 over 128xTN),
// wave owns 64 x TN/2 (4 x TN/32 frags of 16x16). global_load_lds width=16, linear LDS.
// grid = (M/128, N/TN): m-fastest so consecutive blocks share the W panel (L2 reuse).
typedef __attribute__((address_space(3))) unsigned int lds_uint;
typedef const __attribute__((address_space(1))) unsigned int glb_uint;
__device__ __forceinline__ void gload16(const bf16_t* g, bf16_t* l) {
    __builtin_amdgcn_global_load_lds((glb_uint*)g, (lds_uint*)l, 16, 0, 0);
}

template <typename OutT, bool RELU, bool HAS_BIAS, bool HAS_RES, bool NTS, int TN>
__global__ __launch_bounds__(256) void gemm128(const bf16_t* __restrict__ A,
                                               const bf16_t* __restrict__ W,
                                               const float* __restrict__ bias,
                                               const float* __restrict__ res,
                                               OutT* __restrict__ C,
                                               int M, int N, int K) {
    constexpr int NFR = TN / 32;              // n-frags per wave (2 or 4)
    __shared__ __align__(16) bf16_t As[128 * 32];
    __shared__ __align__(16) bf16_t Bs[TN * 32];
    const int m0 = blockIdx.x * 128;
    const int n0 = blockIdx.y * TN;
    const int tid  = threadIdx.x;
    const int wave = tid >> 6;
    const int lane = tid & 63;
    const int q    = lane >> 4;
    const int ln16 = lane & 15;
    const int wr   = wave >> 1;               // row half of tile
    const int wc   = wave & 1;                // col half of tile

    floatx4 acc[4][NFR];
#pragma unroll
    for (int i = 0; i < 4; i++)
#pragma unroll
        for (int j = 0; j < NFR; j++) acc[i][j] = (floatx4){0.f, 0.f, 0.f, 0.f};

    // staging: A — wave covers rows wave*32..+31; B — wave covers TN/4 rows.
    const int srow = lane >> 2;               // 0..15
    const int scol = (lane & 3) * 8;
    const bf16_t* Ag = A + (size_t)(m0 + wave * 32 + srow) * K + scol;
    const bf16_t* Wg = W + (size_t)(n0 + wave * (TN / 4) + srow) * K + scol;
    bf16_t* As0 = &As[wave * 1024];
    bf16_t* Bs0 = &Bs[wave * (TN / 4) * 32];

    for (int k0 = 0; k0 < K; k0 += 32) {
        gload16(Ag + k0, As0);
        gload16(Ag + (size_t)16 * K + k0, As0 + 512);
        gload16(Wg + k0, Bs0);
        if constexpr (TN == 128) gload16(Wg + (size_t)16 * K + k0, Bs0 + 512);
        __syncthreads();                      // compiler drains vmcnt(0) before barrier
        bf16x8 af[4], bfg[NFR];
#pragma unroll
        for (int mt = 0; mt < 4; mt++)
            af[mt] = *(const bf16x8*)&As[(wr * 64 + mt * 16 + ln16) * 32 + q * 8];
#pragma unroll
        for (int nt = 0; nt < NFR; nt++)
            bfg[nt] = *(const bf16x8*)&Bs[(wc * (TN / 2) + nt * 16 + ln16) * 32 + q * 8];
#pragma unroll
        for (int mt = 0; mt < 4; mt++)
#pragma unroll
            for (int nt = 0; nt < NFR; nt++)
                acc[mt][nt] = __builtin_amdgcn_mfma_f32_16x16x32_bf16(af[mt], bfg[nt], acc[mt][nt], 0, 0, 0);
        __syncthreads();
    }

#pragma unroll
    for (int mt = 0; mt < 4; mt++)
#pragma unroll
        for (int nt = 0; nt < NFR; nt++) {
            const int n = n0 + wc * (TN / 2) + nt * 16 + ln16;
            float bv = 0.f;
            if constexpr (HAS_BIAS) bv = bias[n];
#pragma unroll
            for (int r = 0; r < 4; r++) {
                const int m = m0 + wr * 64 + mt * 16 + q * 4 + r;
                float v = acc[mt][nt][r] + bv;
                if constexpr (RELU) v = fmaxf(v, 0.f);
                if constexpr (HAS_RES) v += res[(size_t)m * N + n];
                if constexpr (NTS) {
                    __builtin_nontemporal_store((OutT)v, &C[(size_t)m * N + n]);
                } else {
                    C[(size_t)m * N + n] = (OutT)v;
                }
            }
        }
}

// ---------------------------------------------------------------- flash attention
// One block per (q-tile of 64 rows, b*h). 4 waves; wave w owns q rows w*16..w*16+15.
// Q,K,V row stride ld (768 for separate buffers, 2304 for packed QKV).
__global__ __launch_bounds__(256) void attn_kernel(const bf16_t* __restrict__ Q,
                                                   const bf16_t* __restrict__ K,
                                                   const bf16_t* __restrict__ V,
                                                   bf16_t* __restrict__ ctx,
                                                   int ld) {
    // LDS: Qs [0,4096) elems (reused as Ps after Q-frag hoist), Ks [4096,8192), Vts [8192,12288)
    __shared__ bf16_t smem[12288];
    bf16_t* Qs  = smem;
    bf16_t* Ks  = smem + 4096;
    bf16_t* Vts = smem + 8192;
    bf16_t* Ps  = smem;                      // aliases Qs (dead after frag hoist)

    const int qt  = blockIdx.x;              // 0..15
    const int bh  = blockIdx.y;              // 0..23
    const int b   = bh / N_HEADS;
    const int hh  = bh - b * N_HEADS;
    const int tid  = threadIdx.x;
    const int wave = tid >> 6;
    const int lane = tid & 63;
    const int quad = lane >> 4;
    const int ln16 = lane & 15;
    const int q0   = qt * 64;
    const size_t base = (size_t)(b * SEQ) * ld + hh * DK;

    const int r0 = tid >> 3;                 // 0..31 staging row
    const int cg = tid & 7;                  // col group (8 elems)

    // ---- stage Q tile (natural layout), hoist A-frags
    {
        const bf16_t* src = Q + base + (size_t)q0 * ld;
        *(uint4*)&Qs[r0 * 64 + cg * 8]        = *(const uint4*)(src + (size_t)r0 * ld + cg * 8);
        *(uint4*)&Qs[(r0 + 32) * 64 + cg * 8] = *(const uint4*)(src + (size_t)(r0 + 32) * ld + cg * 8);
    }
    __syncthreads();
    const bf16x8 aq0 = *(const bf16x8*)&Qs[(wave * 16 + ln16) * 64 + quad * 8];
    const bf16x8 aq1 = *(const bf16x8*)&Qs[(wave * 16 + ln16) * 64 + 32 + quad * 8];

    float m_run[4] = {-1e30f, -1e30f, -1e30f, -1e30f};
    float l_run[4] = {0.f, 0.f, 0.f, 0.f};
    floatx4 o[4] = {{0.f, 0.f, 0.f, 0.f}, {0.f, 0.f, 0.f, 0.f},
                    {0.f, 0.f, 0.f, 0.f}, {0.f, 0.f, 0.f, 0.f}};
    const float scale = 0.125f;              // 1/sqrt(64)

    for (int j0 = 0; j0 <= q0; j0 += 64) {
        __syncthreads();                     // prev iter's reads done before restage
        const bf16_t* ksrc = K + base + (size_t)j0 * ld;
        const bf16_t* vsrc = V + base + (size_t)j0 * ld;
#pragma unroll
        for (int half = 0; half < 2; half++) {
            const int j = r0 + half * 32;
            *(uint4*)&Ks[j * 64 + cg * 8] = *(const uint4*)(ksrc + (size_t)j * ld + cg * 8);
            const bf16x8 vv = *(const bf16x8*)(vsrc + (size_t)j * ld + cg * 8);
#pragma unroll
            for (int i = 0; i < 8; i++) {
                const int d = cg * 8 + i;
                Vts[d * 64 + (((j >> 3) ^ cg) << 3) + (j & 7)] = vv[i];
            }
        }
        __syncthreads();

        // ---- S = (Q K^T) * scale   (C-layout: row=quad*4+r, col=nt*16+ln16)
        floatx4 s[4];
#pragma unroll
        for (int nt = 0; nt < 4; nt++) {
            const bf16x8 bk0 = *(const bf16x8*)&Ks[(nt * 16 + ln16) * 64 + quad * 8];
            const bf16x8 bk1 = *(const bf16x8*)&Ks[(nt * 16 + ln16) * 64 + 32 + quad * 8];
            floatx4 z = {0.f, 0.f, 0.f, 0.f};
            z = __builtin_amdgcn_mfma_f32_16x16x32_bf16(aq0, bk0, z, 0, 0, 0);
            z = __builtin_amdgcn_mfma_f32_16x16x32_bf16(aq1, bk1, z, 0, 0, 0);
            s[nt] = z;
        }
        const bool diag = (j0 == q0);
#pragma unroll
        for (int nt = 0; nt < 4; nt++)
#pragma unroll
            for (int r = 0; r < 4; r++) {
                float v = s[nt][r] * scale;
                if (diag && (nt * 16 + ln16 > wave * 16 + quad * 4 + r)) v = -1e30f;
                s[nt][r] = v;
            }

        // ---- online softmax update (rows quad*4+r; reduce over 16 lanes)
        float alpha[4];
#pragma unroll
        for (int r = 0; r < 4; r++) {
            float v = fmaxf(fmaxf(s[0][r], s[1][r]), fmaxf(s[2][r], s[3][r]));
#pragma unroll
            for (int off = 1; off < 16; off <<= 1) v = fmaxf(v, __shfl_xor(v, off, 64));
            const float m_new = fmaxf(m_run[r], v);
            alpha[r] = __expf(m_run[r] - m_new);
            m_run[r] = m_new;
        }
        float rsum[4] = {0.f, 0.f, 0.f, 0.f};
#pragma unroll
        for (int nt = 0; nt < 4; nt++)
#pragma unroll
            for (int r = 0; r < 4; r++) {
                const float p = __expf(s[nt][r] - m_run[r]);
                s[nt][r] = p;
                rsum[r] += p;
            }
#pragma unroll
        for (int r = 0; r < 4; r++) {
            float v = rsum[r];
#pragma unroll
            for (int off = 1; off < 16; off <<= 1) v += __shfl_xor(v, off, 64);
            l_run[r] = l_run[r] * alpha[r] + v;
        }
#pragma unroll
        for (int nt = 0; nt < 4; nt++)
#pragma unroll
            for (int r = 0; r < 4; r++) o[nt][r] *= alpha[r];

        // ---- P: C-layout regs -> per-wave LDS (xor-swizzled) -> A-layout frags
        bf16_t* Pw = Ps + wave * 1024;
#pragma unroll
        for (int nt = 0; nt < 4; nt++)
#pragma unroll
            for (int r = 0; r < 4; r++) {
                const int rr = quad * 4 + r;
                Pw[rr * 64 + (((nt * 2 + (ln16 >> 3)) ^ (rr & 7)) << 3) + (ln16 & 7)] = (bf16_t)s[nt][r];
            }
        const bf16x8 ap0 = *(const bf16x8*)&Pw[ln16 * 64 + ((quad ^ (ln16 & 7)) << 3)];
        const bf16x8 ap1 = *(const bf16x8*)&Pw[ln16 * 64 + (((quad + 4) ^ (ln16 & 7)) << 3)];

        // ---- O += P V   (B-frag from swizzled Vt: row d, k=j)
#pragma unroll
        for (int nt = 0; nt < 4; nt++) {
            const int d  = nt * 16 + ln16;
            const int dd = (nt * 2 + (ln16 >> 3)) & 7;
            const bf16x8 bv0 = *(const bf16x8*)&Vts[d * 64 + ((quad ^ dd) << 3)];
            const bf16x8 bv1 = *(const bf16x8*)&Vts[d * 64 + (((quad + 4) ^ dd) << 3)];
            o[nt] = __builtin_amdgcn_mfma_f32_16x16x32_bf16(ap0, bv0, o[nt], 0, 0, 0);
            o[nt] = __builtin_amdgcn_mfma_f32_16x16x32_bf16(ap1, bv1, o[nt], 0, 0, 0);
        }
    }

    // ---- epilogue: O / l -> ctx (row stride 768)
#pragma unroll
    for (int r = 0; r < 4; r++) {
        const float inv = 1.0f / l_run[r];
        const int m = q0 + wave * 16 + quad * 4 + r;
#pragma unroll
        for (int nt = 0; nt < 4; nt++) {
            ctx[(size_t)(b * SEQ + m) * D_MODEL + hh * DK + nt * 16 + ln16] = (bf16_t)(o[nt][r] * inv);
        }
    }
}

// ---------------------------------------------------------------- launch
extern "C" void kernel_launch(void* const* d_in, const int* in_sizes, int n_in,
                              void* d_out, int out_size, void* d_ws, size_t ws_size,
                              hipStream_t stream) {
    const int*   x    = (const int*)d_in[0];
    const float* tok  = (const float*)d_in[1];
    const float* pos  = (const float*)d_in[2];
    const float* Wq   = (const float*)d_in[3];
    const float* bq   = (const float*)d_in[4];
    const float* Wk   = (const float*)d_in[5];
    const float* bk   = (const float*)d_in[6];
    const float* Wv   = (const float*)d_in[7];
    const float* bv   = (const float*)d_in[8];
    const float* Wo   = (const float*)d_in[9];
    const float* bo   = (const float*)d_in[10];
    const float* W1   = (const float*)d_in[11];
    const float* b1   = (const float*)d_in[12];
    const float* W2   = (const float*)d_in[13];
    const float* b2   = (const float*)d_in[14];
    const float* ln1g = (const float*)d_in[15];
    const float* ln1b = (const float*)d_in[16];
    const float* ln2g = (const float*)d_in[17];
    const float* ln2b = (const float*)d_in[18];
    const float* lnfg = (const float*)d_in[19];
    const float* lnfb = (const float*)d_in[20];

    char* ws = (char*)d_ws;
    // activations
    const size_t OFF_H    = 0;                  // fp32 [2048,768]           6,291,456
    const size_t OFF_Y    = 6291456;            // bf16 [2048,768]           3,145,728
    const size_t OFF_QKV  = 9437184;            // bf16 [2048,2304]          9,437,184
    const size_t OFF_CTX  = 18874368;           // bf16 [2048,768]           3,145,728
    const size_t OFF_FF   = OFF_QKV;            // bf16 [2048,3072] aliases QKV+CTX (dead)
    // converted weights
    const size_t OFF_TOKB = 22020096;           // bf16 [32000,768]         49,152,000
    const size_t OFF_WB   = 71172096;           // bf16 packed weights      56,623,104
    const size_t OFF_BQKV = 127795200;          // fp32 [L,2304]                36,864
    const size_t END_ALL  = 127832064;
    const size_t END_TOKB = OFF_WB;

    const bool big_ws  = ws_size >= END_TOKB;   // tokb fits (round-2 path)
    const bool big2_ws = ws_size >= END_ALL;    // everything fits

    float*  h    = (float*)(ws + OFF_H);
    bf16_t* y    = (bf16_t*)(ws + OFF_Y);
    bf16_t* qkv  = (bf16_t*)(ws + OFF_QKV);
    bf16_t* qb   = qkv;                          // fallback separate buffers reuse region
    bf16_t* kb   = qkv + 2048 * 768;
    bf16_t* vbuf = qkv + 2 * 2048 * 768;
    bf16_t* ctx  = (bf16_t*)(ws + OFF_CTX);
    bf16_t* ff   = (bf16_t*)(ws + OFF_FF);
    bf16_t* tokb = (bf16_t*)(ws + OFF_TOKB);
    bf16_t* wb   = (bf16_t*)(ws + OFF_WB);
    bf16_t* wqkvb = wb;                          // [L][2304][768]
    bf16_t* wob   = wb + 7077888;                // [L][768][768]
    bf16_t* w1b   = wb + 9437184;                // [L][3072][768]
    bf16_t* w2b   = wb + 18874368;               // [L][768][3072]
    float*  bqkv  = (float*)(ws + OFF_BQKV);     // [L][2304]
    float*  outp  = (float*)d_out;

    embed_kernel<<<NROWS, 256, 0, stream>>>(x, tok, pos, h);

    if (big_ws) {
        cvt_bf16_kernel<<<(VOCAB * D_MODEL) / 2048, 256, 0, stream>>>(tok, tokb);
    }
    if (big2_ws) {
        pack_qkvw_kernel<<<(N_LAYERS * 3 * D_MODEL * D_MODEL) / 2048, 256, 0, stream>>>(Wq, Wk, Wv, wqkvb);
        cvt_bf16_kernel<<<(N_LAYERS * D_MODEL * D_MODEL) / 2048, 256, 0, stream>>>(Wo, wob);
        cvt_bf16_kernel<<<(N_LAYERS * FFN * D_MODEL) / 2048, 256, 0, stream>>>(W1, w1b);
        cvt_bf16_kernel<<<(N_LAYERS * FFN * D_MODEL) / 2048, 256, 0, stream>>>(W2, w2b);
        pack_bias_kernel<<<(N_LAYERS * 3 * D_MODEL) / 256, 256, 0, stream>>>(bq, bk, bv, bqkv);
    }

    const dim3 g768(D_MODEL / 64, NROWS / 64);
    const dim3 gffn(FFN / 64, NROWS / 64);
    const dim3 gattn(SEQ / 64, BATCH * N_HEADS);

    for (int l = 0; l < N_LAYERS; l++) {
        const float* Wq_l = Wq + (size_t)l * D_MODEL * D_MODEL;
        const float* Wk_l = Wk + (size_t)l * D_MODEL * D_MODEL;
        const float* Wv_l = Wv + (size_t)l * D_MODEL * D_MODEL;
        const float* Wo_l = Wo + (size_t)l * D_MODEL * D_MODEL;
        const float* W1_l = W1 + (size_t)l * FFN * D_MODEL;
        const float* W2_l = W2 + (size_t)l * D_MODEL * FFN;

        ln_kernel<<<NROWS, 256, 0, stream>>>(h, ln1g + l * D_MODEL, ln1b + l * D_MODEL, y);

        if (big2_ws) {
            // fused QKV: N=2304, bf16 W, bias, out packed [2048,2304]
            gemm128<bf16_t, false, true, false, false, 128>
                <<<dim3(NROWS / 128, (3 * D_MODEL) / 128), 256, 0, stream>>>(
                y, wqkvb + (size_t)l * 3 * D_MODEL * D_MODEL, bqkv + l * 3 * D_MODEL,
                nullptr, qkv, NROWS, 3 * D_MODEL, D_MODEL);

            attn_kernel<<<gattn, 256, 0, stream>>>(qkv, qkv + D_MODEL, qkv + 2 * D_MODEL, ctx, 3 * D_MODEL);

            gemm128<float, false, true, true, false, 64>
                <<<dim3(NROWS / 128, D_MODEL / 64), 256, 0, stream>>>(
                ctx, wob + (size_t)l * D_MODEL * D_MODEL, bo + l * D_MODEL,
                h, h, NROWS, D_MODEL, D_MODEL);

            ln_kernel<<<NROWS, 256, 0, stream>>>(h, ln2g + l * D_MODEL, ln2b + l * D_MODEL, y);

            gemm128<bf16_t, true, true, false, false, 128>
                <<<dim3(NROWS / 128, FFN / 128), 256, 0, stream>>>(
                y, w1b + (size_t)l * FFN * D_MODEL, b1 + l * FFN,
                nullptr, ff, NROWS, FFN, D_MODEL);

            gemm128<float, false, true, true, false, 64>
                <<<dim3(NROWS / 128, D_MODEL / 64), 256, 0, stream>>>(
                ff, w2b + (size_t)l * D_MODEL * FFN, b2 + l * D_MODEL,
                h, h, NROWS, D_MODEL, FFN);
        } else {
            gemm_bt<bf16_t, false, true, false, false><<<g768, 256, 0, stream>>>(
                y, Wq_l, bq + l * D_MODEL, nullptr, qb, NROWS, D_MODEL, D_MODEL);
            gemm_bt<bf16_t, false, true, false, false><<<g768, 256, 0, stream>>>(
                y, Wk_l, bk + l * D_MODEL, nullptr, kb, NROWS, D_MODEL, D_MODEL);
            gemm_bt<bf16_t, false, true, false, false><<<g768, 256, 0, stream>>>(
                y, Wv_l, bv + l * D_MODEL, nullptr, vbuf, NROWS, D_MODEL, D_MODEL);

            attn_kernel<<<gattn, 256, 0, stream>>>(qb, kb, vbuf, ctx, D_MODEL);

            gemm_bt<float, false, true, true, false><<<g768, 256, 0, stream>>>(
                ctx, Wo_l, bo + l * D_MODEL, h, h, NROWS, D_MODEL, D_MODEL);

            ln_kernel<<<NROWS, 256, 0, stream>>>(h, ln2g + l * D_MODEL, ln2b + l * D_MODEL, y);

            gemm_bt<bf16_t, true, true, false, false><<<gffn, 256, 0, stream>>>(
                y, W1_l, b1 + l * FFN, nullptr, ff, NROWS, FFN, D_MODEL);

            gemm_bt<float, false, true, true, false><<<g768, 256, 0, stream>>>(
                ff, W2_l, b2 + l * D_MODEL, h, h, NROWS, D_MODEL, FFN);
        }
    }

    ln_kernel<<<NROWS, 256, 0, stream>>>(h, lnfg, lnfb, y);

    if (big_ws) {
        // 128x128 m97-structure LM head; NT stores keep the 256 MB fp32 C-stream
        // from evicting the bf16 W panels out of L2/L3.
        gemm128<float, false, false, false, true, 128>
            <<<dim3(NROWS / 128, VOCAB / 128), 256, 0, stream>>>(
            y, tokb, nullptr, nullptr, outp, NROWS, VOCAB, D_MODEL);
    } else {
        gemm_bt<float, false, false, false, true><<<dim3(NROWS / 64, VOCAB / 64), 256, 0, stream>>>(
            y, tok, nullptr, nullptr, outp, NROWS, VOCAB, D_MODEL);
    }
}

// Round 4
// 1218.456 us; speedup vs baseline: 1.4859x; 1.0301x over previous
//
#include <hip/hip_runtime.h>
#include <hip/hip_bf16.h>

typedef __bf16 bf16_t;
typedef __bf16 bf16x8 __attribute__((ext_vector_type(8)));
typedef float floatx4 __attribute__((ext_vector_type(4)));

#define D_MODEL 768
#define N_HEADS 12
#define DK 64
#define SEQ 1024
#define BATCH 2
#define NROWS (BATCH * SEQ)
#define FFN 3072
#define VOCAB 32000
#define N_LAYERS 4
#define LN_EPS 1e-5f

// ---------------------------------------------------------------- reductions
__device__ __forceinline__ float block_reduce_256(float v, bool is_max, float* sb) {
#pragma unroll
    for (int off = 32; off > 0; off >>= 1) {
        float o = __shfl_down(v, off, 64);
        v = is_max ? fmaxf(v, o) : (v + o);
    }
    int lane = threadIdx.x & 63, wid = threadIdx.x >> 6;
    if (lane == 0) sb[wid] = v;
    __syncthreads();
    float r = is_max ? fmaxf(fmaxf(sb[0], sb[1]), fmaxf(sb[2], sb[3]))
                     : (sb[0] + sb[1]) + (sb[2] + sb[3]);
    __syncthreads();
    return r;
}

// ---------------------------------------------------------------- embedding
__global__ __launch_bounds__(256) void embed_kernel(const int* __restrict__ x,
                                                    const float* __restrict__ tok,
                                                    const float* __restrict__ pos,
                                                    float* __restrict__ h) {
    int row = blockIdx.x;
    int s = row & (SEQ - 1);
    int t = x[row];
    const float* te = tok + (size_t)t * D_MODEL;
    const float* pe = pos + (size_t)s * D_MODEL;
    float* out = h + (size_t)row * D_MODEL;
    int tid = threadIdx.x;
    out[tid]       = te[tid]       + pe[tid];
    out[tid + 256] = te[tid + 256] + pe[tid + 256];
    out[tid + 512] = te[tid + 512] + pe[tid + 512];
}

// ---------------------------------------------------------------- fp32 -> bf16 convert (8 elems/thread)
__global__ __launch_bounds__(256) void cvt_bf16_kernel(const float* __restrict__ src,
                                                       bf16_t* __restrict__ dst) {
    size_t i = ((size_t)blockIdx.x * 256 + threadIdx.x) * 8;
    const float4 a = *(const float4*)(src + i);
    const float4 b = *(const float4*)(src + i + 4);
    bf16x8 o;
    o[0] = (bf16_t)a.x; o[1] = (bf16_t)a.y; o[2] = (bf16_t)a.z; o[3] = (bf16_t)a.w;
    o[4] = (bf16_t)b.x; o[5] = (bf16_t)b.y; o[6] = (bf16_t)b.z; o[7] = (bf16_t)b.w;
    *(bf16x8*)(dst + i) = o;
}
static_assert((VOCAB * D_MODEL) % 2048 == 0, "cvt tiling");
static_assert((N_LAYERS * D_MODEL * D_MODEL) % 2048 == 0, "cvt tiling");
static_assert((N_LAYERS * FFN * D_MODEL) % 2048 == 0, "cvt tiling");

// ---------------------------------------------------------------- pack Wq/Wk/Wv -> [L][2304][768] bf16
__global__ __launch_bounds__(256) void pack_qkvw_kernel(const float* __restrict__ Wq,
                                                        const float* __restrict__ Wk,
                                                        const float* __restrict__ Wv,
                                                        bf16_t* __restrict__ dst) {
    size_t e = ((size_t)blockIdx.x * 256 + threadIdx.x) * 8;
    const int PER_L = 3 * D_MODEL * D_MODEL;      // 1769472
    const int SEG   = D_MODEL * D_MODEL;          // 589824
    int l   = (int)(e / PER_L);
    int rem = (int)(e - (size_t)l * PER_L);
    int n   = rem / D_MODEL;                      // 0..2303
    int c   = rem - n * D_MODEL;
    int seg = n / D_MODEL;                        // 0,1,2
    int sr  = n - seg * D_MODEL;
    const float* src = (seg == 0 ? Wq : seg == 1 ? Wk : Wv) +
                       (size_t)l * SEG + (size_t)sr * D_MODEL + c;
    const float4 a = *(const float4*)src;
    const float4 b = *(const float4*)(src + 4);
    bf16x8 o;
    o[0] = (bf16_t)a.x; o[1] = (bf16_t)a.y; o[2] = (bf16_t)a.z; o[3] = (bf16_t)a.w;
    o[4] = (bf16_t)b.x; o[5] = (bf16_t)b.y; o[6] = (bf16_t)b.z; o[7] = (bf16_t)b.w;
    *(bf16x8*)(dst + e) = o;
}

// ---------------------------------------------------------------- pack bq/bk/bv -> [L][2304] fp32
__global__ __launch_bounds__(256) void pack_bias_kernel(const float* __restrict__ bq,
                                                        const float* __restrict__ bk,
                                                        const float* __restrict__ bv,
                                                        float* __restrict__ dst) {
    int i = blockIdx.x * 256 + threadIdx.x;       // < L*2304
    int l = i / (3 * D_MODEL);
    int n = i - l * (3 * D_MODEL);
    int seg = n / D_MODEL;
    int sr  = n - seg * D_MODEL;
    dst[i] = (seg == 0 ? bq : seg == 1 ? bk : bv)[l * D_MODEL + sr];
}

// ---------------------------------------------------------------- layernorm
__global__ __launch_bounds__(256) void ln_kernel(const float* __restrict__ h,
                                                 const float* __restrict__ g,
                                                 const float* __restrict__ b,
                                                 bf16_t* __restrict__ y) {
    __shared__ float sb[4];
    int row = blockIdx.x;
    const float* xr = h + (size_t)row * D_MODEL;
    int t = threadIdx.x;
    float v0 = xr[t], v1 = xr[t + 256], v2 = xr[t + 512];
    float s  = block_reduce_256(v0 + v1 + v2, false, sb);
    float s2 = block_reduce_256(v0 * v0 + v1 * v1 + v2 * v2, false, sb);
    float mu  = s * (1.0f / D_MODEL);
    float var = s2 * (1.0f / D_MODEL) - mu * mu;
    float inv = rsqrtf(var + LN_EPS);
    bf16_t* yr = y + (size_t)row * D_MODEL;
    yr[t]       = (bf16_t)((v0 - mu) * inv * g[t]       + b[t]);
    yr[t + 256] = (bf16_t)((v1 - mu) * inv * g[t + 256] + b[t + 256]);
    yr[t + 512] = (bf16_t)((v2 - mu) * inv * g[t + 512] + b[t + 512]);
}

// ---------------------------------------------------------------- legacy GEMM (fp32 W, 64x64) for fallback paths
template <typename OutT, bool RELU, bool HAS_BIAS, bool HAS_RES, bool MSWAP>
__global__ __launch_bounds__(256) void gemm_bt(const bf16_t* __restrict__ A,
                                               const float* __restrict__ W,
                                               const float* __restrict__ bias,
                                               const float* __restrict__ res,
                                               OutT* __restrict__ C,
                                               int M, int N, int K) {
    const int LDR = 40;
    __shared__ bf16_t As[64 * LDR];
    __shared__ bf16_t Bs[64 * LDR];
    const int m0 = (MSWAP ? blockIdx.x : blockIdx.y) * 64;
    const int n0 = (MSWAP ? blockIdx.y : blockIdx.x) * 64;
    const int tid  = threadIdx.x;
    const int wave = tid >> 6;
    const int lane = tid & 63;
    const int q    = lane >> 4;
    const int ln16 = lane & 15;

    floatx4 acc[4] = {{0.f, 0.f, 0.f, 0.f}, {0.f, 0.f, 0.f, 0.f},
                      {0.f, 0.f, 0.f, 0.f}, {0.f, 0.f, 0.f, 0.f}};

    const int srow = tid >> 2;
    const int scol = (tid & 3) * 8;
    const bf16_t* Aptr = A + (size_t)(m0 + srow) * K + scol;
    const float*  Wptr = W + (size_t)(n0 + srow) * K + scol;

    for (int k0 = 0; k0 < K; k0 += 32) {
        *(uint4*)(&As[srow * LDR + scol]) = *(const uint4*)(Aptr + k0);
        float4 w0 = *(const float4*)(Wptr + k0);
        float4 w1 = *(const float4*)(Wptr + k0 + 4);
        bf16x8 wb;
        wb[0] = (bf16_t)w0.x; wb[1] = (bf16_t)w0.y; wb[2] = (bf16_t)w0.z; wb[3] = (bf16_t)w0.w;
        wb[4] = (bf16_t)w1.x; wb[5] = (bf16_t)w1.y; wb[6] = (bf16_t)w1.z; wb[7] = (bf16_t)w1.w;
        *(bf16x8*)(&Bs[srow * LDR + scol]) = wb;
        __syncthreads();
        const bf16x8 a = *(const bf16x8*)(&As[(wave * 16 + ln16) * LDR + q * 8]);
#pragma unroll
        for (int nt = 0; nt < 4; nt++) {
            const bf16x8 b = *(const bf16x8*)(&Bs[(nt * 16 + ln16) * LDR + q * 8]);
            acc[nt] = __builtin_amdgcn_mfma_f32_16x16x32_bf16(a, b, acc[nt], 0, 0, 0);
        }
        __syncthreads();
    }

#pragma unroll
    for (int nt = 0; nt < 4; nt++) {
        const int n = n0 + nt * 16 + ln16;
        float bv = 0.f;
        if constexpr (HAS_BIAS) bv = bias[n];
#pragma unroll
        for (int r = 0; r < 4; r++) {
            const int m = m0 + wave * 16 + q * 4 + r;
            float v = acc[nt][r] + bv;
            if constexpr (RELU) v = fmaxf(v, 0.f);
            if constexpr (HAS_RES) v += res[(size_t)m * N + n];
            C[(size_t)m * N + n] = (OutT)v;
        }
    }
}

// ---------------------------------------------------------------- 128xTN bf16 GEMM, BK=64, swizzled LDS
// C = A(MxK bf16) . W(NxK bf16)^T (+bias)(+relu)(+res). 4 waves (2x2 over 128xTN).
// LDS [rows][64] (128B row stride = full bank wrap). global_load_lds writes linearly,
// so the 16B chunk order within each row is pre-swizzled at the GLOBAL source
// (chunk = (lane&7) ^ (lane>>3)) and reads apply pslot = (kk*4+q) ^ (ln16&7):
// 16 lanes span 8 bank-quads -> 2-way (free). 32 MFMA per 2 barriers (TN=128).
// XSWZ (LM head): XCD-chunked block swizzle so the 16 m-blocks sharing a W panel
// run on ONE XCD's L2 (m157 pattern; requires nwg%8==0, guarded).
typedef __attribute__((address_space(3))) unsigned int lds_uint;
typedef const __attribute__((address_space(1))) unsigned int glb_uint;
__device__ __forceinline__ void gload16(const bf16_t* g, bf16_t* l) {
    __builtin_amdgcn_global_load_lds((glb_uint*)g, (lds_uint*)l, 16, 0, 0);
}

template <typename OutT, bool RELU, bool HAS_BIAS, bool HAS_RES, bool XSWZ, int TN>
__global__ __launch_bounds__(256) void gemm128(const bf16_t* __restrict__ A,
                                               const bf16_t* __restrict__ W,
                                               const float* __restrict__ bias,
                                               const float* __restrict__ res,
                                               OutT* __restrict__ C,
                                               int M, int N, int K) {
    constexpr int NFR = TN / 32;              // n-frags per wave (2 or 4)
    __shared__ __align__(16) bf16_t As[128 * 64];
    __shared__ __align__(16) bf16_t Bs[TN * 64];

    int mb, nb;
    if constexpr (XSWZ) {
        const int nwg = gridDim.x * gridDim.y;
        const int lid = blockIdx.x + blockIdx.y * gridDim.x;
        if ((nwg & 7) == 0) {
            const int swz = (lid & 7) * (nwg >> 3) + (lid >> 3);
            mb = swz % gridDim.x;
            nb = swz / gridDim.x;
        } else { mb = blockIdx.x; nb = blockIdx.y; }
    } else { mb = blockIdx.x; nb = blockIdx.y; }

    const int m0 = mb * 128;
    const int n0 = nb * TN;
    const int tid  = threadIdx.x;
    const int wave = tid >> 6;
    const int lane = tid & 63;
    const int q    = lane >> 4;
    const int ln16 = lane & 15;
    const int wr   = wave >> 1;               // row half of tile
    const int wc   = wave & 1;                // col half of tile

    floatx4 acc[4][NFR];
#pragma unroll
    for (int i = 0; i < 4; i++)
#pragma unroll
        for (int j = 0; j < NFR; j++) acc[i][j] = (floatx4){0.f, 0.f, 0.f, 0.f};

    // staging: each gload16 covers 8 rows x 64 cols. lane -> (row=lane>>3, chunk=lane&7).
    // source chunk pre-swizzled by row parity (row&7 == lane>>3 for all sub-loads).
    const int srow = lane >> 3;               // 0..7
    const int scol = ((lane & 7) ^ srow) * 8; // pre-swizzled 16B chunk
    const bf16_t* Ag = A + (size_t)(m0 + wave * 32 + srow) * K + scol;
    const bf16_t* Wg = W + (size_t)(n0 + wave * (TN / 4) + srow) * K + scol;
    bf16_t* As0 = &As[(wave * 32) * 64];
    bf16_t* Bs0 = &Bs[(wave * (TN / 4)) * 64];

    const int ps = ln16 & 7;                  // read-side swizzle factor

    for (int k0 = 0; k0 < K; k0 += 64) {
#pragma unroll
        for (int i = 0; i < 4; i++)
            gload16(Ag + (size_t)(i * 8) * K + k0, As0 + (i * 8) * 64);
#pragma unroll
        for (int i = 0; i < NFR; i++)
            gload16(Wg + (size_t)(i * 8) * K + k0, Bs0 + (i * 8) * 64);
        __syncthreads();                      // compiler drains vmcnt(0) before barrier

        bf16x8 af[4][2], bfg[NFR][2];
#pragma unroll
        for (int kk = 0; kk < 2; kk++) {
#pragma unroll
            for (int mt = 0; mt < 4; mt++)
                af[mt][kk] = *(const bf16x8*)&As[(wr * 64 + mt * 16 + ln16) * 64 + (((kk * 4 + q) ^ ps) << 3)];
#pragma unroll
            for (int nt = 0; nt < NFR; nt++)
                bfg[nt][kk] = *(const bf16x8*)&Bs[(wc * (TN / 2) + nt * 16 + ln16) * 64 + (((kk * 4 + q) ^ ps) << 3)];
        }
#pragma unroll
        for (int kk = 0; kk < 2; kk++)
#pragma unroll
            for (int mt = 0; mt < 4; mt++)
#pragma unroll
                for (int nt = 0; nt < NFR; nt++)
                    acc[mt][nt] = __builtin_amdgcn_mfma_f32_16x16x32_bf16(af[mt][kk], bfg[nt][kk], acc[mt][nt], 0, 0, 0);
        __syncthreads();
    }

#pragma unroll
    for (int mt = 0; mt < 4; mt++)
#pragma unroll
        for (int nt = 0; nt < NFR; nt++) {
            const int n = n0 + wc * (TN / 2) + nt * 16 + ln16;
            float bv = 0.f;
            if constexpr (HAS_BIAS) bv = bias[n];
#pragma unroll
            for (int r = 0; r < 4; r++) {
                const int m = m0 + wr * 64 + mt * 16 + q * 4 + r;
                float v = acc[mt][nt][r] + bv;
                if constexpr (RELU) v = fmaxf(v, 0.f);
                if constexpr (HAS_RES) v += res[(size_t)m * N + n];
                C[(size_t)m * N + n] = (OutT)v;
            }
        }
}

// ---------------------------------------------------------------- flash attention
// One block per (q-tile of 64 rows, b*h). 4 waves; wave w owns q rows w*16..w*16+15.
// Q,K,V row stride ld (768 for separate buffers, 2304 for packed QKV).
__global__ __launch_bounds__(256) void attn_kernel(const bf16_t* __restrict__ Q,
                                                   const bf16_t* __restrict__ K,
                                                   const bf16_t* __restrict__ V,
                                                   bf16_t* __restrict__ ctx,
                                                   int ld) {
    // LDS: Qs [0,4096) elems (reused as Ps after Q-frag hoist), Ks [4096,8192), Vts [8192,12288)
    __shared__ bf16_t smem[12288];
    bf16_t* Qs  = smem;
    bf16_t* Ks  = smem + 4096;
    bf16_t* Vts = smem + 8192;
    bf16_t* Ps  = smem;                      // aliases Qs (dead after frag hoist)

    const int qt  = blockIdx.x;              // 0..15
    const int bh  = blockIdx.y;              // 0..23
    const int b   = bh / N_HEADS;
    const int hh  = bh - b * N_HEADS;
    const int tid  = threadIdx.x;
    const int wave = tid >> 6;
    const int lane = tid & 63;
    const int quad = lane >> 4;
    const int ln16 = lane & 15;
    const int q0   = qt * 64;
    const size_t base = (size_t)(b * SEQ) * ld + hh * DK;

    const int r0 = tid >> 3;                 // 0..31 staging row
    const int cg = tid & 7;                  // col group (8 elems)

    // ---- stage Q tile (natural layout), hoist A-frags
    {
        const bf16_t* src = Q + base + (size_t)q0 * ld;
        *(uint4*)&Qs[r0 * 64 + cg * 8]        = *(const uint4*)(src + (size_t)r0 * ld + cg * 8);
        *(uint4*)&Qs[(r0 + 32) * 64 + cg * 8] = *(const uint4*)(src + (size_t)(r0 + 32) * ld + cg * 8);
    }
    __syncthreads();
    const bf16x8 aq0 = *(const bf16x8*)&Qs[(wave * 16 + ln16) * 64 + quad * 8];
    const bf16x8 aq1 = *(const bf16x8*)&Qs[(wave * 16 + ln16) * 64 + 32 + quad * 8];

    float m_run[4] = {-1e30f, -1e30f, -1e30f, -1e30f};
    float l_run[4] = {0.f, 0.f, 0.f, 0.f};
    floatx4 o[4] = {{0.f, 0.f, 0.f, 0.f}, {0.f, 0.f, 0.f, 0.f},
                    {0.f, 0.f, 0.f, 0.f}, {0.f, 0.f, 0.f, 0.f}};
    const float scale = 0.125f;              // 1/sqrt(64)

    for (int j0 = 0; j0 <= q0; j0 += 64) {
        __syncthreads();                     // prev iter's reads done before restage
        const bf16_t* ksrc = K + base + (size_t)j0 * ld;
        const bf16_t* vsrc = V + base + (size_t)j0 * ld;
#pragma unroll
        for (int half = 0; half < 2; half++) {
            const int j = r0 + half * 32;
            *(uint4*)&Ks[j * 64 + cg * 8] = *(const uint4*)(ksrc + (size_t)j * ld + cg * 8);
            const bf16x8 vv = *(const bf16x8*)(vsrc + (size_t)j * ld + cg * 8);
#pragma unroll
            for (int i = 0; i < 8; i++) {
                const int d = cg * 8 + i;
                Vts[d * 64 + (((j >> 3) ^ cg) << 3) + (j & 7)] = vv[i];
            }
        }
        __syncthreads();

        // ---- S = (Q K^T) * scale   (C-layout: row=quad*4+r, col=nt*16+ln16)
        floatx4 s[4];
#pragma unroll
        for (int nt = 0; nt < 4; nt++) {
            const bf16x8 bk0 = *(const bf16x8*)&Ks[(nt * 16 + ln16) * 64 + quad * 8];
            const bf16x8 bk1 = *(const bf16x8*)&Ks[(nt * 16 + ln16) * 64 + 32 + quad * 8];
            floatx4 z = {0.f, 0.f, 0.f, 0.f};
            z = __builtin_amdgcn_mfma_f32_16x16x32_bf16(aq0, bk0, z, 0, 0, 0);
            z = __builtin_amdgcn_mfma_f32_16x16x32_bf16(aq1, bk1, z, 0, 0, 0);
            s[nt] = z;
        }
        const bool diag = (j0 == q0);
#pragma unroll
        for (int nt = 0; nt < 4; nt++)
#pragma unroll
            for (int r = 0; r < 4; r++) {
                float v = s[nt][r] * scale;
                if (diag && (nt * 16 + ln16 > wave * 16 + quad * 4 + r)) v = -1e30f;
                s[nt][r] = v;
            }

        // ---- online softmax update (rows quad*4+r; reduce over 16 lanes)
        float alpha[4];
#pragma unroll
        for (int r = 0; r < 4; r++) {
            float v = fmaxf(fmaxf(s[0][r], s[1][r]), fmaxf(s[2][r], s[3][r]));
#pragma unroll
            for (int off = 1; off < 16; off <<= 1) v = fmaxf(v, __shfl_xor(v, off, 64));
            const float m_new = fmaxf(m_run[r], v);
            alpha[r] = __expf(m_run[r] - m_new);
            m_run[r] = m_new;
        }
        float rsum[4] = {0.f, 0.f, 0.f, 0.f};
#pragma unroll
        for (int nt = 0; nt < 4; nt++)
#pragma unroll
            for (int r = 0; r < 4; r++) {
                const float p = __expf(s[nt][r] - m_run[r]);
                s[nt][r] = p;
                rsum[r] += p;
            }
#pragma unroll
        for (int r = 0; r < 4; r++) {
            float v = rsum[r];
#pragma unroll
            for (int off = 1; off < 16; off <<= 1) v += __shfl_xor(v, off, 64);
            l_run[r] = l_run[r] * alpha[r] + v;
        }
#pragma unroll
        for (int nt = 0; nt < 4; nt++)
#pragma unroll
            for (int r = 0; r < 4; r++) o[nt][r] *= alpha[r];

        // ---- P: C-layout regs -> per-wave LDS (xor-swizzled) -> A-layout frags
        bf16_t* Pw = Ps + wave * 1024;
#pragma unroll
        for (int nt = 0; nt < 4; nt++)
#pragma unroll
            for (int r = 0; r < 4; r++) {
                const int rr = quad * 4 + r;
                Pw[rr * 64 + (((nt * 2 + (ln16 >> 3)) ^ (rr & 7)) << 3) + (ln16 & 7)] = (bf16_t)s[nt][r];
            }
        const bf16x8 ap0 = *(const bf16x8*)&Pw[ln16 * 64 + ((quad ^ (ln16 & 7)) << 3)];
        const bf16x8 ap1 = *(const bf16x8*)&Pw[ln16 * 64 + (((quad + 4) ^ (ln16 & 7)) << 3)];

        // ---- O += P V   (B-frag from swizzled Vt: row d, k=j)
#pragma unroll
        for (int nt = 0; nt < 4; nt++) {
            const int d  = nt * 16 + ln16;
            const int dd = (nt * 2 + (ln16 >> 3)) & 7;
            const bf16x8 bv0 = *(const bf16x8*)&Vts[d * 64 + ((quad ^ dd) << 3)];
            const bf16x8 bv1 = *(const bf16x8*)&Vts[d * 64 + (((quad + 4) ^ dd) << 3)];
            o[nt] = __builtin_amdgcn_mfma_f32_16x16x32_bf16(ap0, bv0, o[nt], 0, 0, 0);
            o[nt] = __builtin_amdgcn_mfma_f32_16x16x32_bf16(ap1, bv1, o[nt], 0, 0, 0);
        }
    }

    // ---- epilogue: O / l -> ctx (row stride 768)
#pragma unroll
    for (int r = 0; r < 4; r++) {
        const float inv = 1.0f / l_run[r];
        const int m = q0 + wave * 16 + quad * 4 + r;
#pragma unroll
        for (int nt = 0; nt < 4; nt++) {
            ctx[(size_t)(b * SEQ + m) * D_MODEL + hh * DK + nt * 16 + ln16] = (bf16_t)(o[nt][r] * inv);
        }
    }
}

// ---------------------------------------------------------------- launch
extern "C" void kernel_launch(void* const* d_in, const int* in_sizes, int n_in,
                              void* d_out, int out_size, void* d_ws, size_t ws_size,
                              hipStream_t stream) {
    const int*   x    = (const int*)d_in[0];
    const float* tok  = (const float*)d_in[1];
    const float* pos  = (const float*)d_in[2];
    const float* Wq   = (const float*)d_in[3];
    const float* bq   = (const float*)d_in[4];
    const float* Wk   = (const float*)d_in[5];
    const float* bk   = (const float*)d_in[6];
    const float* Wv   = (const float*)d_in[7];
    const float* bv   = (const float*)d_in[8];
    const float* Wo   = (const float*)d_in[9];
    const float* bo   = (const float*)d_in[10];
    const float* W1   = (const float*)d_in[11];
    const float* b1   = (const float*)d_in[12];
    const float* W2   = (const float*)d_in[13];
    const float* b2   = (const float*)d_in[14];
    const float* ln1g = (const float*)d_in[15];
    const float* ln1b = (const float*)d_in[16];
    const float* ln2g = (const float*)d_in[17];
    const float* ln2b = (const float*)d_in[18];
    const float* lnfg = (const float*)d_in[19];
    const float* lnfb = (const float*)d_in[20];

    char* ws = (char*)d_ws;
    // activations
    const size_t OFF_H    = 0;                  // fp32 [2048,768]           6,291,456
    const size_t OFF_Y    = 6291456;            // bf16 [2048,768]           3,145,728
    const size_t OFF_QKV  = 9437184;            // bf16 [2048,2304]          9,437,184
    const size_t OFF_CTX  = 18874368;           // bf16 [2048,768]           3,145,728
    const size_t OFF_FF   = OFF_QKV;            // bf16 [2048,3072] aliases QKV+CTX (dead)
    // converted weights
    const size_t OFF_TOKB = 22020096;           // bf16 [32000,768]         49,152,000
    const size_t OFF_WB   = 71172096;           // bf16 packed weights      56,623,104
    const size_t OFF_BQKV = 127795200;          // fp32 [L,2304]                36,864
    const size_t END_ALL  = 127832064;
    const size_t END_TOKB = OFF_WB;

    const bool big_ws  = ws_size >= END_TOKB;   // tokb fits (round-2 path)
    const bool big2_ws = ws_size >= END_ALL;    // everything fits

    float*  h    = (float*)(ws + OFF_H);
    bf16_t* y    = (bf16_t*)(ws + OFF_Y);
    bf16_t* qkv  = (bf16_t*)(ws + OFF_QKV);
    bf16_t* qb   = qkv;                          // fallback separate buffers reuse region
    bf16_t* kb   = qkv + 2048 * 768;
    bf16_t* vbuf = qkv + 2 * 2048 * 768;
    bf16_t* ctx  = (bf16_t*)(ws + OFF_CTX);
    bf16_t* ff   = (bf16_t*)(ws + OFF_FF);
    bf16_t* tokb = (bf16_t*)(ws + OFF_TOKB);
    bf16_t* wb   = (bf16_t*)(ws + OFF_WB);
    bf16_t* wqkvb = wb;                          // [L][2304][768]
    bf16_t* wob   = wb + 7077888;                // [L][768][768]
    bf16_t* w1b   = wb + 9437184;                // [L][3072][768]
    bf16_t* w2b   = wb + 18874368;               // [L][768][3072]
    float*  bqkv  = (float*)(ws + OFF_BQKV);     // [L][2304]
    float*  outp  = (float*)d_out;

    embed_kernel<<<NROWS, 256, 0, stream>>>(x, tok, pos, h);

    if (big_ws) {
        cvt_bf16_kernel<<<(VOCAB * D_MODEL) / 2048, 256, 0, stream>>>(tok, tokb);
    }
    if (big2_ws) {
        pack_qkvw_kernel<<<(N_LAYERS * 3 * D_MODEL * D_MODEL) / 2048, 256, 0, stream>>>(Wq, Wk, Wv, wqkvb);
        cvt_bf16_kernel<<<(N_LAYERS * D_MODEL * D_MODEL) / 2048, 256, 0, stream>>>(Wo, wob);
        cvt_bf16_kernel<<<(N_LAYERS * FFN * D_MODEL) / 2048, 256, 0, stream>>>(W1, w1b);
        cvt_bf16_kernel<<<(N_LAYERS * FFN * D_MODEL) / 2048, 256, 0, stream>>>(W2, w2b);
        pack_bias_kernel<<<(N_LAYERS * 3 * D_MODEL) / 256, 256, 0, stream>>>(bq, bk, bv, bqkv);
    }

    const dim3 g768(D_MODEL / 64, NROWS / 64);
    const dim3 gffn(FFN / 64, NROWS / 64);
    const dim3 gattn(SEQ / 64, BATCH * N_HEADS);

    for (int l = 0; l < N_LAYERS; l++) {
        const float* Wq_l = Wq + (size_t)l * D_MODEL * D_MODEL;
        const float* Wk_l = Wk + (size_t)l * D_MODEL * D_MODEL;
        const float* Wv_l = Wv + (size_t)l * D_MODEL * D_MODEL;
        const float* Wo_l = Wo + (size_t)l * D_MODEL * D_MODEL;
        const float* W1_l = W1 + (size_t)l * FFN * D_MODEL;
        const float* W2_l = W2 + (size_t)l * D_MODEL * FFN;

        ln_kernel<<<NROWS, 256, 0, stream>>>(h, ln1g + l * D_MODEL, ln1b + l * D_MODEL, y);

        if (big2_ws) {
            // fused QKV: N=2304, bf16 W, bias, out packed [2048,2304]
            gemm128<bf16_t, false, true, false, false, 128>
                <<<dim3(NROWS / 128, (3 * D_MODEL) / 128), 256, 0, stream>>>(
                y, wqkvb + (size_t)l * 3 * D_MODEL * D_MODEL, bqkv + l * 3 * D_MODEL,
                nullptr, qkv, NROWS, 3 * D_MODEL, D_MODEL);

            attn_kernel<<<gattn, 256, 0, stream>>>(qkv, qkv + D_MODEL, qkv + 2 * D_MODEL, ctx, 3 * D_MODEL);

            gemm128<float, false, true, true, false, 64>
                <<<dim3(NROWS / 128, D_MODEL / 64), 256, 0, stream>>>(
                ctx, wob + (size_t)l * D_MODEL * D_MODEL, bo + l * D_MODEL,
                h, h, NROWS, D_MODEL, D_MODEL);

            ln_kernel<<<NROWS, 256, 0, stream>>>(h, ln2g + l * D_MODEL, ln2b + l * D_MODEL, y);

            gemm128<bf16_t, true, true, false, false, 128>
                <<<dim3(NROWS / 128, FFN / 128), 256, 0, stream>>>(
                y, w1b + (size_t)l * FFN * D_MODEL, b1 + l * FFN,
                nullptr, ff, NROWS, FFN, D_MODEL);

            gemm128<float, false, true, true, false, 64>
                <<<dim3(NROWS / 128, D_MODEL / 64), 256, 0, stream>>>(
                ff, w2b + (size_t)l * D_MODEL * FFN, b2 + l * D_MODEL,
                h, h, NROWS, D_MODEL, FFN);
        } else {
            gemm_bt<bf16_t, false, true, false, false><<<g768, 256, 0, stream>>>(
                y, Wq_l, bq + l * D_MODEL, nullptr, qb, NROWS, D_MODEL, D_MODEL);
            gemm_bt<bf16_t, false, true, false, false><<<g768, 256, 0, stream>>>(
                y, Wk_l, bk + l * D_MODEL, nullptr, kb, NROWS, D_MODEL, D_MODEL);
            gemm_bt<bf16_t, false, true, false, false><<<g768, 256, 0, stream>>>(
                y, Wv_l, bv + l * D_MODEL, nullptr, vbuf, NROWS, D_MODEL, D_MODEL);

            attn_kernel<<<gattn, 256, 0, stream>>>(qb, kb, vbuf, ctx, D_MODEL);

            gemm_bt<float, false, true, true, false><<<g768, 256, 0, stream>>>(
                ctx, Wo_l, bo + l * D_MODEL, h, h, NROWS, D_MODEL, D_MODEL);

            ln_kernel<<<NROWS, 256, 0, stream>>>(h, ln2g + l * D_MODEL, ln2b + l * D_MODEL, y);

            gemm_bt<bf16_t, true, true, false, false><<<gffn, 256, 0, stream>>>(
                y, W1_l, b1 + l * FFN, nullptr, ff, NROWS, FFN, D_MODEL);

            gemm_bt<float, false, true, true, false><<<g768, 256, 0, stream>>>(
                ff, W2_l, b2 + l * D_MODEL, h, h, NROWS, D_MODEL, FFN);
        }
    }

    ln_kernel<<<NROWS, 256, 0, stream>>>(h, lnfg, lnfb, y);

    if (big_ws) {
        // LM head: 128x128, BK=64, XCD-chunked swizzle; regular stores (NT hurt: +70MB writes)
        gemm128<float, false, false, false, true, 128>
            <<<dim3(NROWS / 128, VOCAB / 128), 256, 0, stream>>>(
            y, tokb, nullptr, nullptr, outp, NROWS, VOCAB, D_MODEL);
    } else {
        gemm_bt<float, false, false, false, true><<<dim3(NROWS / 64, VOCAB / 64), 256, 0, stream>>>(
            y, tok, nullptr, nullptr, outp, NROWS, VOCAB, D_MODEL);
    }
}